// Round 22
// baseline (395.163 us; speedup 1.0000x reference)
//
#include <hip/hip_runtime.h>
#include <cstdint>

typedef __attribute__((ext_vector_type(8))) __bf16 bf16x8;
typedef __attribute__((ext_vector_type(4))) float f32x4;
typedef __attribute__((ext_vector_type(8))) unsigned short ushort8v;

__device__ __forceinline__ float b2f(unsigned short u) {
    union { uint32_t i; float f; } w; w.i = ((uint32_t)u) << 16; return w.f;
}
__device__ __forceinline__ unsigned short f2b(float f) {
    union { uint32_t i; float f; } w; w.f = f;
    uint32_t r = (w.i + 0x7FFFu + ((w.i >> 16) & 1u)) >> 16;
    return (unsigned short)r;
}

// 16B global -> LDS direct (wave-uniform LDS base; HW adds lane*16).
__device__ __forceinline__ void gl16(const unsigned short* g, unsigned short* l) {
    __builtin_amdgcn_global_load_lds(
        (const __attribute__((address_space(1))) void*)g,
        (__attribute__((address_space(3))) void*)l,
        16, 0, 0);
}

// bijective XCD-chunk remap (m204)
__device__ __forceinline__ int swz8(int wg, int nwg) {
    const int q = nwg >> 3, r = nwg & 7;
    const int xcd = wg & 7, idx = wg >> 3;
    return (xcd < r) ? (xcd * (q + 1) + idx)
                     : (r * (q + 1) + (xcd - r) * q + idx);
}

// ---------------------------------------------------------------------------
// Merged pre-pass kernel (validated r19/r20): LN(x), LN(xf), silu(emb0),
// weight cvt+transpose in ONE launch via block-range dispatch.
// ---------------------------------------------------------------------------
template <int DIM>
__device__ __forceinline__ void ln_body(int bid, const float* __restrict__ in,
                                        const float* __restrict__ g,
                                        const float* __restrict__ b,
                                        unsigned short* __restrict__ out) {
    const int row = bid * 4 + (threadIdx.x >> 6);
    const int ln = threadIdx.x & 63;
    constexpr int PL = DIM / 64;
    float v[PL];
    const size_t base = (size_t)row * DIM + (size_t)ln * PL;
    const float4* p4 = (const float4*)(in + base);
#pragma unroll
    for (int c = 0; c < PL / 4; ++c) {
        const float4 t = p4[c];
        v[c * 4 + 0] = t.x; v[c * 4 + 1] = t.y; v[c * 4 + 2] = t.z; v[c * 4 + 3] = t.w;
    }
    float s = 0.f, s2 = 0.f;
#pragma unroll
    for (int c = 0; c < PL; ++c) { s += v[c]; s2 += v[c] * v[c]; }
    for (int o = 1; o < 64; o <<= 1) { s += __shfl_xor(s, o); s2 += __shfl_xor(s2, o); }
    const float mean = s / DIM;
    const float rstd = rsqrtf(s2 / DIM - mean * mean + 1e-5f);
    const float* gp = g + ln * PL;
    const float* bp = b + ln * PL;
#pragma unroll
    for (int c0 = 0; c0 < PL; c0 += 8) {
        ushort8v yv;
#pragma unroll
        for (int j = 0; j < 8; ++j) {
            const int c = c0 + j;
            yv[j] = f2b((v[c] - mean) * rstd * gp[c] + bp[c]);
        }
        *(ushort8v*)(out + base + c0) = yv;
    }
}

__global__ __launch_bounds__(256) void k_pre(
    const float* __restrict__ x, const float* __restrict__ ln_g, const float* __restrict__ ln_b,
    unsigned short* __restrict__ xn,
    const float* __restrict__ xf, const float* __restrict__ tln_g, const float* __restrict__ tln_b,
    unsigned short* __restrict__ xfn,
    const float* __restrict__ emb, unsigned short* __restrict__ se,
    const float* __restrict__ Wq, const float* __restrict__ Wk,
    const float* __restrict__ Wv, const float* __restrict__ We,
    const float* __restrict__ Wo,
    unsigned short* __restrict__ wqt, unsigned short* __restrict__ wkvt,
    unsigned short* __restrict__ wet, unsigned short* __restrict__ wot) {
    __shared__ float s[32][33];
    int bid = blockIdx.x;
    if (bid < 7776) { ln_body<1024>(bid, x, ln_g, ln_b, xn); return; }
    bid -= 7776;
    if (bid < 2464) { ln_body<512>(bid, xf, tln_g, tln_b, xfn); return; }
    bid -= 2464;
    if (bid < 512) {
        const int i = bid * 256 + threadIdx.x;
        const int b = i >> 10, k = i & 1023;
        const float f = emb[(size_t)b * (243 * 1024) + k];
        se[i] = f2b(f / (1.f + __expf(-f)));
        return;
    }
    bid -= 512;
    const float* in; unsigned short* out; int R, C;
    if (bid < 1024)      { in = Wq; out = wqt;              R = 1024; C = 1024; }
    else if (bid < 1536) { bid -= 1024; in = Wk; out = wkvt;             R = 512;  C = 1024; }
    else if (bid < 2048) { bid -= 1536; in = Wv; out = wkvt + 1024 * 512; R = 512;  C = 1024; }
    else if (bid < 4096) { bid -= 2048; in = We; out = wet;              R = 1024; C = 2048; }
    else                 { bid -= 4096; in = Wo; out = wot;              R = 1024; C = 1024; }
    const int ctiles = C >> 5;
    const int c0 = (bid % ctiles) * 32, r0 = (bid / ctiles) * 32;
    const int tx = threadIdx.x & 31, ty = threadIdx.x >> 5;
#pragma unroll
    for (int i = 0; i < 4; ++i)
        s[ty + i * 8][tx] = in[(size_t)(r0 + ty + i * 8) * C + c0 + tx];
    __syncthreads();
#pragma unroll
    for (int i = 0; i < 4; ++i)
        out[(size_t)(c0 + ty + i * 8) * R + r0 + tx] = f2b(s[tx][ty + i * 8]);
}

// ---------------------------------------------------------------------------
// GEMM body r22: 128x256 tile, 8 waves, 2m x 4n wave grid, DOUBLE-BUFFERED
// LDS with 2-tile-deep prefetch, counted vmcnt + raw s_barrier (T4, m201
// recipe: no sched_barrier pins; lgkmcnt(0) anchor protects WAR on LDS).
// vmcnt never drains to 0 in the main loop (6 loads/wave/tile in flight).
// epi 0: C0 bf16 | 1: Cf f32 = acc+bias+X | 2: KV split | 3: Cf f32
// ---------------------------------------------------------------------------
__device__ __forceinline__ void mm_body(
    int u, int NN,
    const unsigned short* __restrict__ A, const unsigned short* __restrict__ Bt,
    const float* __restrict__ bias0, const float* __restrict__ bias1,
    unsigned short* __restrict__ C0, unsigned short* __restrict__ C1,
    float* __restrict__ Cf, const float* __restrict__ X,
    int N, int K, int epi,
    unsigned short* sA, unsigned short* sB) {
    const int tid = threadIdx.x, wv = tid >> 6, ln = tid & 63;
    const int wm = wv >> 2, wn = wv & 3;          // 2m x 4n wave grid
    const int ln15 = ln & 15, lg = ln >> 4;
    const int m0 = (u / NN) * 128, n0 = (u % NN) * 256;

    const f32x4 fz = {0.f, 0.f, 0.f, 0.f};
    f32x4 acc[4][4];
#pragma unroll
    for (int i = 0; i < 4; ++i)
#pragma unroll
        for (int j = 0; j < 4; ++j) acc[i][j] = fz;

    const int lrow = ln >> 3;
    const int sslot = (ln & 7) ^ lrow;
    const unsigned short* ga = A + (size_t)(m0 + wv * 16 + lrow) * K + sslot * 8;
    const unsigned short* gb = Bt + (size_t)(n0 + wv * 32 + lrow) * K + sslot * 8;

    const int NT = K >> 6;
    auto STAGE = [&](int t, int buf) {
        const int k0 = t << 6;
        unsigned short* const lA = sA + buf * (128 * 64) + (wv * 16) * 64;
        unsigned short* const lB = sB + buf * (256 * 64) + (wv * 32) * 64;
#pragma unroll
        for (int i = 0; i < 2; ++i)
            gl16(ga + k0 + (size_t)i * 8 * K, lA + i * 8 * 64);
#pragma unroll
        for (int i = 0; i < 4; ++i)
            gl16(gb + k0 + (size_t)i * 8 * K, lB + i * 8 * 64);
    };

    // prologue: stage tiles 0 and 1 (6 loads each per wave)
    STAGE(0, 0);
    STAGE(1, 1);
    asm volatile("s_waitcnt vmcnt(6)" ::: "memory");   // own t0 loads landed
    __builtin_amdgcn_s_barrier();                       // all waves' t0 landed

    for (int t = 0; t < NT; ++t) {
        const int cur = t & 1;
        const unsigned short* bA = sA + cur * (128 * 64);
        const unsigned short* bB = sB + cur * (256 * 64);
        bf16x8 af[4][2], bf[4][2];
#pragma unroll
        for (int i = 0; i < 4; ++i) {
            const int ra2 = wm * 64 + i * 16 + ln15;
            const int rb2 = wn * 64 + i * 16 + ln15;
#pragma unroll
            for (int ks = 0; ks < 2; ++ks) {
                const int slot = ks * 4 + lg;
                af[i][ks] = *(const bf16x8*)(bA + ra2 * 64 + ((slot ^ (ra2 & 7)) * 8));
                bf[i][ks] = *(const bf16x8*)(bB + rb2 * 64 + ((slot ^ (rb2 & 7)) * 8));
            }
        }
        __builtin_amdgcn_s_setprio(1);
#pragma unroll
        for (int mi = 0; mi < 4; ++mi)
#pragma unroll
            for (int ni = 0; ni < 4; ++ni) {
                acc[mi][ni] = __builtin_amdgcn_mfma_f32_16x16x32_bf16(af[mi][0], bf[ni][0], acc[mi][ni], 0, 0, 0);
                acc[mi][ni] = __builtin_amdgcn_mfma_f32_16x16x32_bf16(af[mi][1], bf[ni][1], acc[mi][ni], 0, 0, 0);
            }
        __builtin_amdgcn_s_setprio(0);
        // anchor: all this wave's ds_reads of buf[cur] complete before the
        // barrier, so the upcoming STAGE into buf[cur] cannot race them.
        asm volatile("s_waitcnt lgkmcnt(0)" ::: "memory");
        __builtin_amdgcn_s_barrier();        // all waves done with buf[cur]
        if (t + 2 < NT) {
            STAGE(t + 2, cur);               // overwrite buf[cur] (2-deep)
            asm volatile("s_waitcnt vmcnt(6)" ::: "memory");  // t+1 landed; t+2 in flight
            __builtin_amdgcn_s_barrier();
        } else if (t + 1 < NT) {
            asm volatile("s_waitcnt vmcnt(0)" ::: "memory");  // final tile landed
            __builtin_amdgcn_s_barrier();
        }
    }

    const int colB = n0 + wn * 64;
    const int rowB = m0 + wm * 64;
#pragma unroll
    for (int mi = 0; mi < 4; ++mi) {
#pragma unroll
        for (int ni = 0; ni < 4; ++ni) {
            const int col = colB + ni * 16 + ln15;
            const int row = rowB + mi * 16 + lg * 4;
            float bvv;
            if (epi == 2) bvv = (col < 1024) ? bias0[col] : bias1[col - 1024];
            else bvv = bias0[col];
#pragma unroll
            for (int r2 = 0; r2 < 4; ++r2) {
                const float v = acc[mi][ni][r2] + bvv;
                if (epi == 0) {
                    C0[(size_t)(row + r2) * N + col] = f2b(v);
                } else if (epi == 1) {
                    Cf[(size_t)(row + r2) * N + col] = v + X[(size_t)(row + r2) * N + col];
                } else if (epi == 2) {
                    if (col < 1024) C0[(size_t)(row + r2) * 1024 + col] = f2b(v);
                    else C1[(size_t)(row + r2) * 1024 + (col - 1024)] = f2b(v);
                } else {
                    Cf[(size_t)(row + r2) * N + col] = v;
                }
            }
        }
    }
}

// Fused projections: Q (972 blocks) + KV (616) + EO (8) in one launch.
__global__ __launch_bounds__(512, 2) void k_mm3(
    const unsigned short* __restrict__ xn, const unsigned short* __restrict__ wqt,
    const float* __restrict__ bq, unsigned short* __restrict__ qb,
    const unsigned short* __restrict__ xfn, const unsigned short* __restrict__ wkvt,
    const float* __restrict__ bk, const float* __restrict__ bv,
    unsigned short* __restrict__ kb, unsigned short* __restrict__ vb,
    const unsigned short* __restrict__ se, const unsigned short* __restrict__ wet,
    const float* __restrict__ be, float* __restrict__ eo) {
    __shared__ __align__(16) unsigned short sA[2 * 128 * 64];
    __shared__ __align__(16) unsigned short sB[2 * 256 * 64];
    const int wg = blockIdx.x;
    if (wg < 972) {
        mm_body(swz8(wg, 972), 4, xn, wqt, bq, nullptr, qb, nullptr, nullptr, nullptr,
                1024, 1024, 0, sA, sB);
    } else if (wg < 1588) {
        mm_body(swz8(wg - 972, 616), 8, xfn, wkvt, bk, bv, kb, vb, nullptr, nullptr,
                2048, 512, 2, sA, sB);
    } else {
        mm_body(wg - 1588, 8, se, wet, be, nullptr, nullptr, nullptr, eo, nullptr,
                2048, 1024, 3, sA, sB);
    }
}

// O-proj + residual -> f32 out
__global__ __launch_bounds__(512, 2) void k_mm1(
    const unsigned short* __restrict__ actb, const unsigned short* __restrict__ wot,
    const float* __restrict__ bo, const float* __restrict__ x,
    float* __restrict__ outp) {
    __shared__ __align__(16) unsigned short sA[2 * 128 * 64];
    __shared__ __align__(16) unsigned short sB[2 * 256 * 64];
    mm_body(swz8(blockIdx.x, 972), 4, actb, wot, bo, nullptr, nullptr, nullptr,
            outp, x, 1024, 1024, 1, sA, sB);
}

// ---------------------------------------------------------------------------
// MFMA cross-attention (validated r21): LDS union + setprio.
// ---------------------------------------------------------------------------
__global__ __launch_bounds__(256, 2) void k_attn_m(const unsigned short* __restrict__ Q,
                                                   const unsigned short* __restrict__ Kb,
                                                   const unsigned short* __restrict__ Vb,
                                                   unsigned short* __restrict__ Y) {
    __shared__ __align__(16) unsigned short sK[80 * 64];
    __shared__ __align__(16) unsigned short sV[64 * 96];
    __shared__ __align__(16) unsigned short sU[4 * 16 * 104];
    unsigned short* const sVr = sU;
    const int bh = blockIdx.x;
    const int b = bh >> 4, h = bh & 15;
    const int tid = threadIdx.x, wv = tid >> 6, ln = tid & 63;
    const int ln15 = ln & 15, lg = ln >> 4;
    unsigned short* const sP = sU + wv * (16 * 104);

    for (int c = tid; c < 640; c += 256) {
        const int n = c >> 3, ci = c & 7;
        uint4 kv = make_uint4(0u, 0u, 0u, 0u), vv = make_uint4(0u, 0u, 0u, 0u);
        if (n < 77) {
            const size_t o = (size_t)(b * 77 + n) * 1024 + h * 64 + ci * 8;
            kv = *(const uint4*)(Kb + o);
            vv = *(const uint4*)(Vb + o);
        }
        *(uint4*)((char*)sK + n * 128 + ((ci * 16) ^ ((n & 7) << 4))) = kv;
        *(uint4*)(sVr + n * 72 + ci * 8) = vv;
    }
    bf16x8 qf[4][2];
    const size_t qbase = (size_t)b * (243 * 1024) + h * 64;
#pragma unroll
    for (int mi = 0; mi < 4; ++mi) {
        int t = wv * 64 + mi * 16 + ln15;
        if (t > 242) t = 242;
#pragma unroll
        for (int ks = 0; ks < 2; ++ks)
            qf[mi][ks] = *(const bf16x8*)(Q + qbase + (size_t)t * 1024 + ks * 32 + lg * 8);
    }
    __syncthreads();

    for (int i = tid; i < 64 * 96; i += 256) {
        const int d = i / 96, n = i - d * 96;
        sV[i] = (n < 80) ? sVr[n * 72 + d] : (unsigned short)0;
    }
    __syncthreads();

    for (int i = ln; i < 16 * 24; i += 64) {
        const int rr = i / 24, cc = i - rr * 24;
        sP[rr * 104 + 80 + cc] = 0;
    }

    const f32x4 fz = {0.f, 0.f, 0.f, 0.f};
#pragma unroll
    for (int mi = 0; mi < 4; ++mi) {
        f32x4 sc[5];
#pragma unroll
        for (int ci = 0; ci < 5; ++ci) sc[ci] = fz;
        __builtin_amdgcn_s_setprio(1);
#pragma unroll
        for (int ci = 0; ci < 5; ++ci) {
            const int n = ci * 16 + ln15;
#pragma unroll
            for (int ks = 0; ks < 2; ++ks) {
                const int kk = ks * 32 + lg * 8;
                bf16x8 kf = *(const bf16x8*)((const char*)sK + n * 128 + ((kk * 2) ^ ((n & 7) << 4)));
                sc[ci] = __builtin_amdgcn_mfma_f32_16x16x32_bf16(qf[mi][ks], kf, sc[ci], 0, 0, 0);
            }
        }
        __builtin_amdgcn_s_setprio(0);
#pragma unroll
        for (int r = 0; r < 4; ++r) {
            float e[5];
            float mx = -1e30f;
#pragma unroll
            for (int ci = 0; ci < 5; ++ci) {
                const int n = ci * 16 + ln15;
                const float vv = (n < 77) ? sc[ci][r] * 0.125f : -1e30f;
                e[ci] = vv;
                mx = fmaxf(mx, vv);
            }
            mx = fmaxf(mx, __shfl_xor(mx, 1));
            mx = fmaxf(mx, __shfl_xor(mx, 2));
            mx = fmaxf(mx, __shfl_xor(mx, 4));
            mx = fmaxf(mx, __shfl_xor(mx, 8));
            float ssum = 0.f;
#pragma unroll
            for (int ci = 0; ci < 5; ++ci) {
                const int n = ci * 16 + ln15;
                const float ev = (n < 77) ? __expf(e[ci] - mx) : 0.f;
                e[ci] = ev;
                ssum += ev;
            }
            ssum += __shfl_xor(ssum, 1);
            ssum += __shfl_xor(ssum, 2);
            ssum += __shfl_xor(ssum, 4);
            ssum += __shfl_xor(ssum, 8);
            const float inv = 1.f / ssum;
            const int prow = lg * 4 + r;
#pragma unroll
            for (int ci = 0; ci < 5; ++ci)
                sP[prow * 104 + ci * 16 + ln15] = f2b(e[ci] * inv);
        }
        f32x4 ya[4];
#pragma unroll
        for (int di = 0; di < 4; ++di) ya[di] = fz;
        __builtin_amdgcn_s_setprio(1);
#pragma unroll
        for (int ks = 0; ks < 3; ++ks) {
            bf16x8 pa = *(const bf16x8*)(sP + ln15 * 104 + ks * 32 + lg * 8);
#pragma unroll
            for (int di = 0; di < 4; ++di) {
                bf16x8 vf = *(const bf16x8*)(sV + (di * 16 + ln15) * 96 + ks * 32 + lg * 8);
                ya[di] = __builtin_amdgcn_mfma_f32_16x16x32_bf16(pa, vf, ya[di], 0, 0, 0);
            }
        }
        __builtin_amdgcn_s_setprio(0);
        unsigned short* sy = sP;
#pragma unroll
        for (int di = 0; di < 4; ++di)
#pragma unroll
            for (int r = 0; r < 4; ++r)
                sy[(lg * 4 + r) * 72 + di * 16 + ln15] = f2b(ya[di][r]);
        const int tb = wv * 64 + mi * 16;
#pragma unroll
        for (int j = 0; j < 2; ++j) {
            const int k = ln * 2 + j;
            const int row = k >> 3, off = (k & 7) * 8;
            const int t = tb + row;
            if (t < 243)
                *(uint4*)(Y + qbase + (size_t)t * 1024 + off) = *(const uint4*)(sy + row * 72 + off);
        }
    }
}

// ---------------------------------------------------------------------------
// Stylization (vectorized, validated)
// ---------------------------------------------------------------------------
__global__ __launch_bounds__(256) void k_act(const unsigned short* __restrict__ y,
                                             const float* __restrict__ eo,
                                             const float* __restrict__ g,
                                             const float* __restrict__ b,
                                             unsigned short* __restrict__ out) {
    const int row = blockIdx.x * 4 + (threadIdx.x >> 6);
    const int ln = threadIdx.x & 63;
    const int bb = row / 243;
    float v[16];
    const size_t base = (size_t)row * 1024 + ln * 16;
#pragma unroll
    for (int c0 = 0; c0 < 16; c0 += 8) {
        const ushort8v t = *(const ushort8v*)(y + base + c0);
#pragma unroll
        for (int j = 0; j < 8; ++j) v[c0 + j] = b2f(t[j]);
    }
    float s = 0.f, s2 = 0.f;
#pragma unroll
    for (int c = 0; c < 16; ++c) { s += v[c]; s2 += v[c] * v[c]; }
    for (int o = 1; o < 64; o <<= 1) { s += __shfl_xor(s, o); s2 += __shfl_xor(s2, o); }
    const float mean = s / 1024.f;
    const float rstd = rsqrtf(s2 / 1024.f - mean * mean + 1e-5f);
    const float* gp = g + ln * 16;
    const float* bp = b + ln * 16;
    const float* sc = eo + (size_t)bb * 2048 + ln * 16;
    const float* sh = sc + 1024;
#pragma unroll
    for (int c0 = 0; c0 < 16; c0 += 8) {
        ushort8v yv;
#pragma unroll
        for (int j = 0; j < 8; ++j) {
            const int c = c0 + j;
            const float nl = (v[c] - mean) * rstd * gp[c] + bp[c];
            const float hh = nl * (1.f + sc[c]) + sh[c];
            yv[j] = f2b(hh / (1.f + __expf(-hh)));
        }
        *(ushort8v*)(out + base + c0) = yv;
    }
}

// ---------------------------------------------------------------------------
extern "C" void kernel_launch(void* const* d_in, const int* in_sizes, int n_in,
                              void* d_out, int out_size, void* d_ws, size_t ws_size,
                              hipStream_t stream) {
    (void)in_sizes; (void)n_in; (void)out_size; (void)ws_size;

    const float* x     = (const float*)d_in[0];
    const float* xf    = (const float*)d_in[1];
    const float* emb   = (const float*)d_in[2];
    const float* ln_g  = (const float*)d_in[3];
    const float* ln_b  = (const float*)d_in[4];
    const float* tln_g = (const float*)d_in[5];
    const float* tln_b = (const float*)d_in[6];
    const float* Wq    = (const float*)d_in[7];
    const float* bq    = (const float*)d_in[8];
    const float* Wk    = (const float*)d_in[9];
    const float* bk    = (const float*)d_in[10];
    const float* Wv    = (const float*)d_in[11];
    const float* bv    = (const float*)d_in[12];
    const float* We    = (const float*)d_in[13];
    const float* be    = (const float*)d_in[14];
    const float* ln2_g = (const float*)d_in[15];
    const float* ln2_b = (const float*)d_in[16];
    const float* Wo    = (const float*)d_in[17];
    const float* bo    = (const float*)d_in[18];
    float* outp = (float*)d_out;

    char* ws = (char*)d_ws;
    constexpr size_t o_wq   = 0;
    constexpr size_t o_wkv  = o_wq + 2097152;
    constexpr size_t o_we   = o_wkv + 2097152;
    constexpr size_t o_wo   = o_we + 4194304;
    constexpr size_t o_se   = o_wo + 2097152;
    constexpr size_t o_eo   = o_se + 262144;
    constexpr size_t o_xn   = o_eo + 1048576;
    constexpr size_t o_qb   = o_xn + 63700992;
    constexpr size_t o_xfn  = o_qb + 63700992;
    constexpr size_t o_kb   = o_xfn + 10092544;
    constexpr size_t o_vb   = o_kb + 20185088;

    unsigned short* wqt  = (unsigned short*)(ws + o_wq);
    unsigned short* wkvt = (unsigned short*)(ws + o_wkv);
    unsigned short* wet  = (unsigned short*)(ws + o_we);
    unsigned short* wot  = (unsigned short*)(ws + o_wo);
    unsigned short* se   = (unsigned short*)(ws + o_se);
    float*          eo   = (float*)(ws + o_eo);
    unsigned short* xn   = (unsigned short*)(ws + o_xn);
    unsigned short* yb   = xn;                      // alias: xn dead after Q-GEMM
    unsigned short* qb   = (unsigned short*)(ws + o_qb);
    unsigned short* actb = qb;                      // alias: q dead after attention
    unsigned short* xfn  = (unsigned short*)(ws + o_xfn);
    unsigned short* kb   = (unsigned short*)(ws + o_kb);
    unsigned short* vb   = (unsigned short*)(ws + o_vb);

    // merged pre-passes: LN(x) 7776 | LN(xf) 2464 | silu 512 | cvt 5120
    k_pre<<<15872, 256, 0, stream>>>(x, ln_g, ln_b, xn,
                                     xf, tln_g, tln_b, xfn,
                                     emb, se,
                                     Wq, Wk, Wv, We, Wo,
                                     wqt, wkvt, wet, wot);

    // fused projections: Q + KV + EO in one launch (pipelined mm_body)
    k_mm3<<<1596, 512, 0, stream>>>(xn, wqt, bq, qb,
                                    xfn, wkvt, bk, bv, kb, vb,
                                    se, wet, be, eo);

    // attention
    k_attn_m<<<2048, 256, 0, stream>>>(qb, kb, vb, yb);

    // stylization
    k_act<<<7776, 256, 0, stream>>>(yb, eo, ln2_g, ln2_b, actb);

    // output projection + residual -> d_out (f32)
    k_mm1<<<972, 512, 0, stream>>>(actb, wot, bo, x, outp);
}

// Round 23
// 340.010 us; speedup vs baseline: 1.1622x; 1.1622x over previous
//
#include <hip/hip_runtime.h>
#include <cstdint>

typedef __attribute__((ext_vector_type(8))) __bf16 bf16x8;
typedef __attribute__((ext_vector_type(4))) float f32x4;
typedef __attribute__((ext_vector_type(8))) unsigned short ushort8v;

__device__ __forceinline__ float b2f(unsigned short u) {
    union { uint32_t i; float f; } w; w.i = ((uint32_t)u) << 16; return w.f;
}
__device__ __forceinline__ unsigned short f2b(float f) {
    union { uint32_t i; float f; } w; w.f = f;
    uint32_t r = (w.i + 0x7FFFu + ((w.i >> 16) & 1u)) >> 16;
    return (unsigned short)r;
}

// 16B global -> LDS direct (wave-uniform LDS base; HW adds lane*16).
__device__ __forceinline__ void gl16(const unsigned short* g, unsigned short* l) {
    __builtin_amdgcn_global_load_lds(
        (const __attribute__((address_space(1))) void*)g,
        (__attribute__((address_space(3))) void*)l,
        16, 0, 0);
}

// bijective XCD-chunk remap (m204)
__device__ __forceinline__ int swz8(int wg, int nwg) {
    const int q = nwg >> 3, r = nwg & 7;
    const int xcd = wg & 7, idx = wg >> 3;
    return (xcd < r) ? (xcd * (q + 1) + idx)
                     : (r * (q + 1) + (xcd - r) * q + idx);
}

// ---------------------------------------------------------------------------
// Merged pre-pass kernel (validated r19/r20): LN(x), LN(xf), silu(emb0),
// weight cvt+transpose in ONE launch via block-range dispatch.
// ---------------------------------------------------------------------------
template <int DIM>
__device__ __forceinline__ void ln_body(int bid, const float* __restrict__ in,
                                        const float* __restrict__ g,
                                        const float* __restrict__ b,
                                        unsigned short* __restrict__ out) {
    const int row = bid * 4 + (threadIdx.x >> 6);
    const int ln = threadIdx.x & 63;
    constexpr int PL = DIM / 64;
    float v[PL];
    const size_t base = (size_t)row * DIM + (size_t)ln * PL;
    const float4* p4 = (const float4*)(in + base);
#pragma unroll
    for (int c = 0; c < PL / 4; ++c) {
        const float4 t = p4[c];
        v[c * 4 + 0] = t.x; v[c * 4 + 1] = t.y; v[c * 4 + 2] = t.z; v[c * 4 + 3] = t.w;
    }
    float s = 0.f, s2 = 0.f;
#pragma unroll
    for (int c = 0; c < PL; ++c) { s += v[c]; s2 += v[c] * v[c]; }
    for (int o = 1; o < 64; o <<= 1) { s += __shfl_xor(s, o); s2 += __shfl_xor(s2, o); }
    const float mean = s / DIM;
    const float rstd = rsqrtf(s2 / DIM - mean * mean + 1e-5f);
    const float* gp = g + ln * PL;
    const float* bp = b + ln * PL;
#pragma unroll
    for (int c0 = 0; c0 < PL; c0 += 8) {
        ushort8v yv;
#pragma unroll
        for (int j = 0; j < 8; ++j) {
            const int c = c0 + j;
            yv[j] = f2b((v[c] - mean) * rstd * gp[c] + bp[c]);
        }
        *(ushort8v*)(out + base + c0) = yv;
    }
}

__global__ __launch_bounds__(256) void k_pre(
    const float* __restrict__ x, const float* __restrict__ ln_g, const float* __restrict__ ln_b,
    unsigned short* __restrict__ xn,
    const float* __restrict__ xf, const float* __restrict__ tln_g, const float* __restrict__ tln_b,
    unsigned short* __restrict__ xfn,
    const float* __restrict__ emb, unsigned short* __restrict__ se,
    const float* __restrict__ Wq, const float* __restrict__ Wk,
    const float* __restrict__ Wv, const float* __restrict__ We,
    const float* __restrict__ Wo,
    unsigned short* __restrict__ wqt, unsigned short* __restrict__ wkvt,
    unsigned short* __restrict__ wet, unsigned short* __restrict__ wot) {
    __shared__ float s[32][33];
    int bid = blockIdx.x;
    if (bid < 7776) { ln_body<1024>(bid, x, ln_g, ln_b, xn); return; }
    bid -= 7776;
    if (bid < 2464) { ln_body<512>(bid, xf, tln_g, tln_b, xfn); return; }
    bid -= 2464;
    if (bid < 512) {
        const int i = bid * 256 + threadIdx.x;
        const int b = i >> 10, k = i & 1023;
        const float f = emb[(size_t)b * (243 * 1024) + k];
        se[i] = f2b(f / (1.f + __expf(-f)));
        return;
    }
    bid -= 512;
    const float* in; unsigned short* out; int R, C;
    if (bid < 1024)      { in = Wq; out = wqt;              R = 1024; C = 1024; }
    else if (bid < 1536) { bid -= 1024; in = Wk; out = wkvt;             R = 512;  C = 1024; }
    else if (bid < 2048) { bid -= 1536; in = Wv; out = wkvt + 1024 * 512; R = 512;  C = 1024; }
    else if (bid < 4096) { bid -= 2048; in = We; out = wet;              R = 1024; C = 2048; }
    else                 { bid -= 4096; in = Wo; out = wot;              R = 1024; C = 1024; }
    const int ctiles = C >> 5;
    const int c0 = (bid % ctiles) * 32, r0 = (bid / ctiles) * 32;
    const int tx = threadIdx.x & 31, ty = threadIdx.x >> 5;
#pragma unroll
    for (int i = 0; i < 4; ++i)
        s[ty + i * 8][tx] = in[(size_t)(r0 + ty + i * 8) * C + c0 + tx];
    __syncthreads();
#pragma unroll
    for (int i = 0; i < 4; ++i)
        out[(size_t)(c0 + ty + i * 8) * R + r0 + tx] = f2b(s[tx][ty + i * 8]);
}

// ---------------------------------------------------------------------------
// GEMM body (r18/r20-validated, BEST): 128x256 tile, 8 waves, 2m x 4n wave
// grid, per-wave 64x64 output, 2-barrier K-loop, m97 gl16 staging, XOR swizzle.
// epi 0: C0 bf16 | 1: Cf f32 = acc+bias+X | 2: KV split | 3: Cf f32
// ---------------------------------------------------------------------------
__device__ __forceinline__ void mm_body(
    int u, int NN,
    const unsigned short* __restrict__ A, const unsigned short* __restrict__ Bt,
    const float* __restrict__ bias0, const float* __restrict__ bias1,
    unsigned short* __restrict__ C0, unsigned short* __restrict__ C1,
    float* __restrict__ Cf, const float* __restrict__ X,
    int N, int K, int epi,
    unsigned short* sA, unsigned short* sB) {
    const int tid = threadIdx.x, wv = tid >> 6, ln = tid & 63;
    const int wm = wv >> 2, wn = wv & 3;          // 2m x 4n wave grid
    const int ln15 = ln & 15, lg = ln >> 4;
    const int m0 = (u / NN) * 128, n0 = (u % NN) * 256;

    const f32x4 fz = {0.f, 0.f, 0.f, 0.f};
    f32x4 acc[4][4];
#pragma unroll
    for (int i = 0; i < 4; ++i)
#pragma unroll
        for (int j = 0; j < 4; ++j) acc[i][j] = fz;

    const int lrow = ln >> 3;
    const int sslot = (ln & 7) ^ lrow;
    const unsigned short* ga = A + (size_t)(m0 + wv * 16 + lrow) * K + sslot * 8;
    const unsigned short* gb = Bt + (size_t)(n0 + wv * 32 + lrow) * K + sslot * 8;
    unsigned short* const lA = sA + (wv * 16) * 64;
    unsigned short* const lB = sB + (wv * 32) * 64;

    for (int k0 = 0; k0 < K; k0 += 64) {
#pragma unroll
        for (int i = 0; i < 2; ++i)
            gl16(ga + k0 + (size_t)i * 8 * K, lA + i * 8 * 64);
#pragma unroll
        for (int i = 0; i < 4; ++i)
            gl16(gb + k0 + (size_t)i * 8 * K, lB + i * 8 * 64);
        __syncthreads();
        bf16x8 af[4][2], bf[4][2];
#pragma unroll
        for (int i = 0; i < 4; ++i) {
            const int ra2 = wm * 64 + i * 16 + ln15;
            const int rb2 = wn * 64 + i * 16 + ln15;
#pragma unroll
            for (int ks = 0; ks < 2; ++ks) {
                const int slot = ks * 4 + lg;
                af[i][ks] = *(const bf16x8*)(sA + ra2 * 64 + ((slot ^ (ra2 & 7)) * 8));
                bf[i][ks] = *(const bf16x8*)(sB + rb2 * 64 + ((slot ^ (rb2 & 7)) * 8));
            }
        }
#pragma unroll
        for (int mi = 0; mi < 4; ++mi)
#pragma unroll
            for (int ni = 0; ni < 4; ++ni) {
                acc[mi][ni] = __builtin_amdgcn_mfma_f32_16x16x32_bf16(af[mi][0], bf[ni][0], acc[mi][ni], 0, 0, 0);
                acc[mi][ni] = __builtin_amdgcn_mfma_f32_16x16x32_bf16(af[mi][1], bf[ni][1], acc[mi][ni], 0, 0, 0);
            }
        __syncthreads();
    }

    const int colB = n0 + wn * 64;
    const int rowB = m0 + wm * 64;
#pragma unroll
    for (int mi = 0; mi < 4; ++mi) {
#pragma unroll
        for (int ni = 0; ni < 4; ++ni) {
            const int col = colB + ni * 16 + ln15;
            const int row = rowB + mi * 16 + lg * 4;
            float bvv;
            if (epi == 2) bvv = (col < 1024) ? bias0[col] : bias1[col - 1024];
            else bvv = bias0[col];
#pragma unroll
            for (int r2 = 0; r2 < 4; ++r2) {
                const float v = acc[mi][ni][r2] + bvv;
                if (epi == 0) {
                    C0[(size_t)(row + r2) * N + col] = f2b(v);
                } else if (epi == 1) {
                    Cf[(size_t)(row + r2) * N + col] = v + X[(size_t)(row + r2) * N + col];
                } else if (epi == 2) {
                    if (col < 1024) C0[(size_t)(row + r2) * 1024 + col] = f2b(v);
                    else C1[(size_t)(row + r2) * 1024 + (col - 1024)] = f2b(v);
                } else {
                    Cf[(size_t)(row + r2) * N + col] = v;
                }
            }
        }
    }
}

// Fused projections: Q (972 blocks) + KV (616) + EO (8) in one launch.
__global__ __launch_bounds__(512, 2) void k_mm3(
    const unsigned short* __restrict__ xn, const unsigned short* __restrict__ wqt,
    const float* __restrict__ bq, unsigned short* __restrict__ qb,
    const unsigned short* __restrict__ xfn, const unsigned short* __restrict__ wkvt,
    const float* __restrict__ bk, const float* __restrict__ bv,
    unsigned short* __restrict__ kb, unsigned short* __restrict__ vb,
    const unsigned short* __restrict__ se, const unsigned short* __restrict__ wet,
    const float* __restrict__ be, float* __restrict__ eo) {
    __shared__ __align__(16) unsigned short sA[128 * 64];
    __shared__ __align__(16) unsigned short sB[256 * 64];
    const int wg = blockIdx.x;
    if (wg < 972) {
        mm_body(swz8(wg, 972), 4, xn, wqt, bq, nullptr, qb, nullptr, nullptr, nullptr,
                1024, 1024, 0, sA, sB);
    } else if (wg < 1588) {
        mm_body(swz8(wg - 972, 616), 8, xfn, wkvt, bk, bv, kb, vb, nullptr, nullptr,
                2048, 512, 2, sA, sB);
    } else {
        mm_body(wg - 1588, 8, se, wet, be, nullptr, nullptr, nullptr, eo, nullptr,
                2048, 1024, 3, sA, sB);
    }
}

// O-proj + residual -> f32 out
__global__ __launch_bounds__(512, 2) void k_mm1(
    const unsigned short* __restrict__ actb, const unsigned short* __restrict__ wot,
    const float* __restrict__ bo, const float* __restrict__ x,
    float* __restrict__ outp) {
    __shared__ __align__(16) unsigned short sA[128 * 64];
    __shared__ __align__(16) unsigned short sB[256 * 64];
    mm_body(swz8(blockIdx.x, 972), 4, actb, wot, bo, nullptr, nullptr, nullptr,
            outp, x, 1024, 1024, 1, sA, sB);
}

// ---------------------------------------------------------------------------
// MFMA cross-attention (validated r21): LDS union (35.8 KB) + setprio.
// ---------------------------------------------------------------------------
__global__ __launch_bounds__(256, 2) void k_attn_m(const unsigned short* __restrict__ Q,
                                                   const unsigned short* __restrict__ Kb,
                                                   const unsigned short* __restrict__ Vb,
                                                   unsigned short* __restrict__ Y) {
    __shared__ __align__(16) unsigned short sK[80 * 64];
    __shared__ __align__(16) unsigned short sV[64 * 96];
    __shared__ __align__(16) unsigned short sU[4 * 16 * 104];
    unsigned short* const sVr = sU;
    const int bh = blockIdx.x;
    const int b = bh >> 4, h = bh & 15;
    const int tid = threadIdx.x, wv = tid >> 6, ln = tid & 63;
    const int ln15 = ln & 15, lg = ln >> 4;
    unsigned short* const sP = sU + wv * (16 * 104);

    for (int c = tid; c < 640; c += 256) {
        const int n = c >> 3, ci = c & 7;
        uint4 kv = make_uint4(0u, 0u, 0u, 0u), vv = make_uint4(0u, 0u, 0u, 0u);
        if (n < 77) {
            const size_t o = (size_t)(b * 77 + n) * 1024 + h * 64 + ci * 8;
            kv = *(const uint4*)(Kb + o);
            vv = *(const uint4*)(Vb + o);
        }
        *(uint4*)((char*)sK + n * 128 + ((ci * 16) ^ ((n & 7) << 4))) = kv;
        *(uint4*)(sVr + n * 72 + ci * 8) = vv;
    }
    bf16x8 qf[4][2];
    const size_t qbase = (size_t)b * (243 * 1024) + h * 64;
#pragma unroll
    for (int mi = 0; mi < 4; ++mi) {
        int t = wv * 64 + mi * 16 + ln15;
        if (t > 242) t = 242;
#pragma unroll
        for (int ks = 0; ks < 2; ++ks)
            qf[mi][ks] = *(const bf16x8*)(Q + qbase + (size_t)t * 1024 + ks * 32 + lg * 8);
    }
    __syncthreads();

    for (int i = tid; i < 64 * 96; i += 256) {
        const int d = i / 96, n = i - d * 96;
        sV[i] = (n < 80) ? sVr[n * 72 + d] : (unsigned short)0;
    }
    __syncthreads();

    for (int i = ln; i < 16 * 24; i += 64) {
        const int rr = i / 24, cc = i - rr * 24;
        sP[rr * 104 + 80 + cc] = 0;
    }

    const f32x4 fz = {0.f, 0.f, 0.f, 0.f};
#pragma unroll
    for (int mi = 0; mi < 4; ++mi) {
        f32x4 sc[5];
#pragma unroll
        for (int ci = 0; ci < 5; ++ci) sc[ci] = fz;
        __builtin_amdgcn_s_setprio(1);
#pragma unroll
        for (int ci = 0; ci < 5; ++ci) {
            const int n = ci * 16 + ln15;
#pragma unroll
            for (int ks = 0; ks < 2; ++ks) {
                const int kk = ks * 32 + lg * 8;
                bf16x8 kf = *(const bf16x8*)((const char*)sK + n * 128 + ((kk * 2) ^ ((n & 7) << 4)));
                sc[ci] = __builtin_amdgcn_mfma_f32_16x16x32_bf16(qf[mi][ks], kf, sc[ci], 0, 0, 0);
            }
        }
        __builtin_amdgcn_s_setprio(0);
#pragma unroll
        for (int r = 0; r < 4; ++r) {
            float e[5];
            float mx = -1e30f;
#pragma unroll
            for (int ci = 0; ci < 5; ++ci) {
                const int n = ci * 16 + ln15;
                const float vv = (n < 77) ? sc[ci][r] * 0.125f : -1e30f;
                e[ci] = vv;
                mx = fmaxf(mx, vv);
            }
            mx = fmaxf(mx, __shfl_xor(mx, 1));
            mx = fmaxf(mx, __shfl_xor(mx, 2));
            mx = fmaxf(mx, __shfl_xor(mx, 4));
            mx = fmaxf(mx, __shfl_xor(mx, 8));
            float ssum = 0.f;
#pragma unroll
            for (int ci = 0; ci < 5; ++ci) {
                const int n = ci * 16 + ln15;
                const float ev = (n < 77) ? __expf(e[ci] - mx) : 0.f;
                e[ci] = ev;
                ssum += ev;
            }
            ssum += __shfl_xor(ssum, 1);
            ssum += __shfl_xor(ssum, 2);
            ssum += __shfl_xor(ssum, 4);
            ssum += __shfl_xor(ssum, 8);
            const float inv = 1.f / ssum;
            const int prow = lg * 4 + r;
#pragma unroll
            for (int ci = 0; ci < 5; ++ci)
                sP[prow * 104 + ci * 16 + ln15] = f2b(e[ci] * inv);
        }
        f32x4 ya[4];
#pragma unroll
        for (int di = 0; di < 4; ++di) ya[di] = fz;
        __builtin_amdgcn_s_setprio(1);
#pragma unroll
        for (int ks = 0; ks < 3; ++ks) {
            bf16x8 pa = *(const bf16x8*)(sP + ln15 * 104 + ks * 32 + lg * 8);
#pragma unroll
            for (int di = 0; di < 4; ++di) {
                bf16x8 vf = *(const bf16x8*)(sV + (di * 16 + ln15) * 96 + ks * 32 + lg * 8);
                ya[di] = __builtin_amdgcn_mfma_f32_16x16x32_bf16(pa, vf, ya[di], 0, 0, 0);
            }
        }
        __builtin_amdgcn_s_setprio(0);
        unsigned short* sy = sP;
#pragma unroll
        for (int di = 0; di < 4; ++di)
#pragma unroll
            for (int r = 0; r < 4; ++r)
                sy[(lg * 4 + r) * 72 + di * 16 + ln15] = f2b(ya[di][r]);
        const int tb = wv * 64 + mi * 16;
#pragma unroll
        for (int j = 0; j < 2; ++j) {
            const int k = ln * 2 + j;
            const int row = k >> 3, off = (k & 7) * 8;
            const int t = tb + row;
            if (t < 243)
                *(uint4*)(Y + qbase + (size_t)t * 1024 + off) = *(const uint4*)(sy + row * 72 + off);
        }
    }
}

// ---------------------------------------------------------------------------
// Stylization (vectorized, validated)
// ---------------------------------------------------------------------------
__global__ __launch_bounds__(256) void k_act(const unsigned short* __restrict__ y,
                                             const float* __restrict__ eo,
                                             const float* __restrict__ g,
                                             const float* __restrict__ b,
                                             unsigned short* __restrict__ out) {
    const int row = blockIdx.x * 4 + (threadIdx.x >> 6);
    const int ln = threadIdx.x & 63;
    const int bb = row / 243;
    float v[16];
    const size_t base = (size_t)row * 1024 + ln * 16;
#pragma unroll
    for (int c0 = 0; c0 < 16; c0 += 8) {
        const ushort8v t = *(const ushort8v*)(y + base + c0);
#pragma unroll
        for (int j = 0; j < 8; ++j) v[c0 + j] = b2f(t[j]);
    }
    float s = 0.f, s2 = 0.f;
#pragma unroll
    for (int c = 0; c < 16; ++c) { s += v[c]; s2 += v[c] * v[c]; }
    for (int o = 1; o < 64; o <<= 1) { s += __shfl_xor(s, o); s2 += __shfl_xor(s2, o); }
    const float mean = s / 1024.f;
    const float rstd = rsqrtf(s2 / 1024.f - mean * mean + 1e-5f);
    const float* gp = g + ln * 16;
    const float* bp = b + ln * 16;
    const float* sc = eo + (size_t)bb * 2048 + ln * 16;
    const float* sh = sc + 1024;
#pragma unroll
    for (int c0 = 0; c0 < 16; c0 += 8) {
        ushort8v yv;
#pragma unroll
        for (int j = 0; j < 8; ++j) {
            const int c = c0 + j;
            const float nl = (v[c] - mean) * rstd * gp[c] + bp[c];
            const float hh = nl * (1.f + sc[c]) + sh[c];
            yv[j] = f2b(hh / (1.f + __expf(-hh)));
        }
        *(ushort8v*)(out + base + c0) = yv;
    }
}

// ---------------------------------------------------------------------------
extern "C" void kernel_launch(void* const* d_in, const int* in_sizes, int n_in,
                              void* d_out, int out_size, void* d_ws, size_t ws_size,
                              hipStream_t stream) {
    (void)in_sizes; (void)n_in; (void)out_size; (void)ws_size;

    const float* x     = (const float*)d_in[0];
    const float* xf    = (const float*)d_in[1];
    const float* emb   = (const float*)d_in[2];
    const float* ln_g  = (const float*)d_in[3];
    const float* ln_b  = (const float*)d_in[4];
    const float* tln_g = (const float*)d_in[5];
    const float* tln_b = (const float*)d_in[6];
    const float* Wq    = (const float*)d_in[7];
    const float* bq    = (const float*)d_in[8];
    const float* Wk    = (const float*)d_in[9];
    const float* bk    = (const float*)d_in[10];
    const float* Wv    = (const float*)d_in[11];
    const float* bv    = (const float*)d_in[12];
    const float* We    = (const float*)d_in[13];
    const float* be    = (const float*)d_in[14];
    const float* ln2_g = (const float*)d_in[15];
    const float* ln2_b = (const float*)d_in[16];
    const float* Wo    = (const float*)d_in[17];
    const float* bo    = (const float*)d_in[18];
    float* outp = (float*)d_out;

    char* ws = (char*)d_ws;
    constexpr size_t o_wq   = 0;
    constexpr size_t o_wkv  = o_wq + 2097152;
    constexpr size_t o_we   = o_wkv + 2097152;
    constexpr size_t o_wo   = o_we + 4194304;
    constexpr size_t o_se   = o_wo + 2097152;
    constexpr size_t o_eo   = o_se + 262144;
    constexpr size_t o_xn   = o_eo + 1048576;
    constexpr size_t o_qb   = o_xn + 63700992;
    constexpr size_t o_xfn  = o_qb + 63700992;
    constexpr size_t o_kb   = o_xfn + 10092544;
    constexpr size_t o_vb   = o_kb + 20185088;

    unsigned short* wqt  = (unsigned short*)(ws + o_wq);
    unsigned short* wkvt = (unsigned short*)(ws + o_wkv);
    unsigned short* wet  = (unsigned short*)(ws + o_we);
    unsigned short* wot  = (unsigned short*)(ws + o_wo);
    unsigned short* se   = (unsigned short*)(ws + o_se);
    float*          eo   = (float*)(ws + o_eo);
    unsigned short* xn   = (unsigned short*)(ws + o_xn);
    unsigned short* yb   = xn;                      // alias: xn dead after Q-GEMM
    unsigned short* qb   = (unsigned short*)(ws + o_qb);
    unsigned short* actb = qb;                      // alias: q dead after attention
    unsigned short* xfn  = (unsigned short*)(ws + o_xfn);
    unsigned short* kb   = (unsigned short*)(ws + o_kb);
    unsigned short* vb   = (unsigned short*)(ws + o_vb);

    // merged pre-passes: LN(x) 7776 | LN(xf) 2464 | silu 512 | cvt 5120
    k_pre<<<15872, 256, 0, stream>>>(x, ln_g, ln_b, xn,
                                     xf, tln_g, tln_b, xfn,
                                     emb, se,
                                     Wq, Wk, Wv, We, Wo,
                                     wqt, wkvt, wet, wot);

    // fused projections: Q + KV + EO in one launch (r18/r20 geometry)
    k_mm3<<<1596, 512, 0, stream>>>(xn, wqt, bq, qb,
                                    xfn, wkvt, bk, bv, kb, vb,
                                    se, wet, be, eo);

    // attention (LDS-union + setprio, r21)
    k_attn_m<<<2048, 256, 0, stream>>>(qb, kb, vb, yb);

    // stylization
    k_act<<<7776, 256, 0, stream>>>(yb, eo, ln2_g, ln2_b, actb);

    // output projection + residual -> d_out (f32)
    k_mm1<<<972, 512, 0, stream>>>(actb, wot, bo, x, outp);
}